// Round 2
// baseline (7994.247 us; speedup 1.0000x reference)
//
#include <hip/hip_runtime.h>

#define N_NODES 100000
#define N_EDGES 1600000
#define D_FEAT  48   // 12 float4 per row

// One thread per edge: out[dst] += w * x[src]  (f32 atomics)
__global__ void spmm_scatter_kernel(const float* __restrict__ xin,
                                    const float* __restrict__ w,
                                    const int*   __restrict__ src,
                                    const int*   __restrict__ dst,
                                    float*       __restrict__ out) {
    int e = blockIdx.x * blockDim.x + threadIdx.x;
    if (e >= N_EDGES) return;
    float we = w[e];
    int s = src[e];
    int d = dst[e];
    const float4* __restrict__ xrow = reinterpret_cast<const float4*>(xin + (size_t)s * D_FEAT);
    float* __restrict__ orow = out + (size_t)d * D_FEAT;
#pragma unroll
    for (int i = 0; i < D_FEAT / 4; ++i) {
        float4 v = xrow[i];
        atomicAdd(orow + 4 * i + 0, we * v.x);
        atomicAdd(orow + 4 * i + 1, we * v.y);
        atomicAdd(orow + 4 * i + 2, we * v.z);
        atomicAdd(orow + 4 * i + 3, we * v.w);
    }
}

extern "C" void kernel_launch(void* const* d_in, const int* in_sizes, int n_in,
                              void* d_out, int out_size, void* d_ws, size_t ws_size,
                              hipStream_t stream) {
    const float* x   = (const float*)d_in[0];
    const float* ew  = (const float*)d_in[1];
    const int*   esrc = (const int*)d_in[2];
    const int*   edst = (const int*)d_in[3];
    float* out = (float*)d_out;
    float* tmp = (float*)d_ws;   // N_NODES * D_FEAT floats = 19.2 MB

    const size_t feat_bytes = (size_t)N_NODES * D_FEAT * sizeof(float);

    dim3 block(256);
    dim3 grid((N_EDGES + 255) / 256);

    // Pass 1: tmp = A @ x
    hipMemsetAsync(tmp, 0, feat_bytes, stream);
    spmm_scatter_kernel<<<grid, block, 0, stream>>>(x, ew, esrc, edst, tmp);

    // Pass 2: out = A @ tmp
    hipMemsetAsync(out, 0, feat_bytes, stream);
    spmm_scatter_kernel<<<grid, block, 0, stream>>>(tmp, ew, esrc, edst, out);
}

// Round 3
// 610.164 us; speedup vs baseline: 13.1018x; 13.1018x over previous
//
#include <hip/hip_runtime.h>

#define N_NODES 100000
#define N_EDGES 1600000
#define D_FEAT  48

// ---------------- CSR build ----------------

__global__ void hist_kernel(const int* __restrict__ dst, int* __restrict__ counts) {
    int e = blockIdx.x * blockDim.x + threadIdx.x;
    if (e < N_EDGES) atomicAdd(&counts[dst[e]], 1);
}

// Single-block scan over N_NODES counts -> row_ptr (exclusive), cursor copy.
__global__ void scan_kernel(const int* __restrict__ counts,
                            int* __restrict__ row_ptr,
                            int* __restrict__ cursor) {
    __shared__ int sdata[1024];
    const int T = 1024;
    const int chunk = (N_NODES + T - 1) / T;  // 98
    int t = threadIdx.x;
    int begin = t * chunk;
    int end   = begin + chunk; if (end > N_NODES) end = N_NODES;
    int s = 0;
    for (int i = begin; i < end; ++i) s += counts[i];
    sdata[t] = s;
    __syncthreads();
    // Hillis-Steele inclusive scan of per-thread sums
    for (int off = 1; off < T; off <<= 1) {
        int v = (t >= off) ? sdata[t - off] : 0;
        __syncthreads();
        sdata[t] += v;
        __syncthreads();
    }
    int offset = sdata[t] - s;  // exclusive prefix for this chunk
    for (int i = begin; i < end; ++i) {
        row_ptr[i] = offset;
        cursor[i]  = offset;
        offset += counts[i];
    }
    if (t == 0) row_ptr[N_NODES] = sdata[T - 1];
}

// Scatter edges into dst-sorted (src, weight) records.
__global__ void bucket_kernel(const float* __restrict__ w,
                              const int*   __restrict__ src,
                              const int*   __restrict__ dst,
                              int*         __restrict__ cursor,
                              int2*        __restrict__ recs) {
    int e = blockIdx.x * blockDim.x + threadIdx.x;
    if (e < N_EDGES) {
        int d = dst[e];
        int pos = atomicAdd(&cursor[d], 1);
        recs[pos] = make_int2(src[e], __float_as_int(w[e]));
    }
}

// ---------------- SpMM gather (atomic-free) ----------------
// 16 threads per node, 3 feats per thread (16*3 = 48).
__global__ void spmm_gather_kernel(const float* __restrict__ xin,
                                   const int2*  __restrict__ recs,
                                   const int*   __restrict__ row_ptr,
                                   float*       __restrict__ out) {
    int tid = blockIdx.x * blockDim.x + threadIdx.x;
    int n = tid >> 4;
    int l = tid & 15;
    if (n >= N_NODES) return;
    int start = row_ptr[n];
    int end   = row_ptr[n + 1];
    float a0 = 0.f, a1 = 0.f, a2 = 0.f;
    for (int e = start; e < end; ++e) {
        int2 r = recs[e];                       // broadcast within the 16-lane group
        float we = __int_as_float(r.y);
        const float* xr = xin + (size_t)r.x * D_FEAT + l * 3;
        a0 += we * xr[0];
        a1 += we * xr[1];
        a2 += we * xr[2];
    }
    float* orow = out + (size_t)n * D_FEAT + l * 3;
    orow[0] = a0; orow[1] = a1; orow[2] = a2;
}

extern "C" void kernel_launch(void* const* d_in, const int* in_sizes, int n_in,
                              void* d_out, int out_size, void* d_ws, size_t ws_size,
                              hipStream_t stream) {
    const float* x    = (const float*)d_in[0];
    const float* ew   = (const float*)d_in[1];
    const int*   esrc = (const int*)d_in[2];
    const int*   edst = (const int*)d_in[3];
    float* out = (float*)d_out;

    // Workspace layout (16B-aligned chunks)
    char* ws = (char*)d_ws;
    float* tmp     = (float*)ws;                            // 19,200,000 B
    ws += (size_t)N_NODES * D_FEAT * sizeof(float);
    int2* recs     = (int2*)ws;                             // 12,800,000 B
    ws += (size_t)N_EDGES * sizeof(int2);
    int* row_ptr   = (int*)ws;                              // 400,004 B
    ws += ((size_t)(N_NODES + 1) * sizeof(int) + 15) & ~15ull;
    int* cursor    = (int*)ws;                              // 400,000 B
    ws += ((size_t)N_NODES * sizeof(int) + 15) & ~15ull;
    int* counts    = (int*)ws;                              // 400,000 B

    dim3 blk(256);
    dim3 grid_edges((N_EDGES + 255) / 256);
    dim3 grid_nodes(((size_t)N_NODES * 16 + 255) / 256);

    // CSR build (once; shared by both passes)
    hipMemsetAsync(counts, 0, (size_t)N_NODES * sizeof(int), stream);
    hist_kernel<<<grid_edges, blk, 0, stream>>>(edst, counts);
    scan_kernel<<<1, 1024, 0, stream>>>(counts, row_ptr, cursor);
    bucket_kernel<<<grid_edges, blk, 0, stream>>>(ew, esrc, edst, cursor, recs);

    // Pass 1: tmp = A @ x ; Pass 2: out = A @ tmp
    spmm_gather_kernel<<<grid_nodes, blk, 0, stream>>>(x,   recs, row_ptr, tmp);
    spmm_gather_kernel<<<grid_nodes, blk, 0, stream>>>(tmp, recs, row_ptr, out);
}

// Round 4
// 398.890 us; speedup vs baseline: 20.0412x; 1.5297x over previous
//
#include <hip/hip_runtime.h>

#define N_NODES 100000
#define N_EDGES 1600000
#define D_FEAT  48

#define SCAN_T     256
#define SCAN_PER_T 2
#define SCAN_CHUNK (SCAN_T * SCAN_PER_T)                       // 512
#define SCAN_NB    ((N_NODES + SCAN_CHUNK - 1) / SCAN_CHUNK)   // 196

// ---------------- CSR build ----------------

__global__ void hist_kernel(const int* __restrict__ dst, int* __restrict__ counts) {
    int e = blockIdx.x * blockDim.x + threadIdx.x;
    if (e < N_EDGES) atomicAdd(&counts[dst[e]], 1);
}

// Phase A: per-block sums of counts
__global__ void scan_partial_kernel(const int* __restrict__ counts,
                                    int* __restrict__ block_sums) {
    __shared__ int sdata[SCAN_T];
    int b = blockIdx.x, t = threadIdx.x;
    int base = b * SCAN_CHUNK + t * SCAN_PER_T;
    int s = 0;
#pragma unroll
    for (int i = 0; i < SCAN_PER_T; ++i) {
        int idx = base + i;
        if (idx < N_NODES) s += counts[idx];
    }
    sdata[t] = s;
    __syncthreads();
    for (int off = SCAN_T / 2; off > 0; off >>= 1) {
        if (t < off) sdata[t] += sdata[t + off];
        __syncthreads();
    }
    if (t == 0) block_sums[b] = sdata[0];
}

// Phase B: single block scans the 196 block sums -> exclusive block offsets + total
__global__ void scan_blocksums_kernel(const int* __restrict__ block_sums,
                                      int* __restrict__ block_offs,
                                      int* __restrict__ row_ptr) {
    __shared__ int sdata[SCAN_T];
    int t = threadIdx.x;
    int v = (t < SCAN_NB) ? block_sums[t] : 0;
    sdata[t] = v;
    __syncthreads();
    for (int off = 1; off < SCAN_T; off <<= 1) {
        int u = (t >= off) ? sdata[t - off] : 0;
        __syncthreads();
        sdata[t] += u;
        __syncthreads();
    }
    if (t < SCAN_NB) block_offs[t] = sdata[t] - v;   // exclusive
    if (t == SCAN_T - 1) row_ptr[N_NODES] = sdata[t]; // total (== N_EDGES)
}

// Phase C: per-block exclusive scan + global offset -> row_ptr, cursor
__global__ void scan_write_kernel(const int* __restrict__ counts,
                                  const int* __restrict__ block_offs,
                                  int* __restrict__ row_ptr,
                                  int* __restrict__ cursor) {
    __shared__ int sdata[SCAN_T];
    int b = blockIdx.x, t = threadIdx.x;
    int base = b * SCAN_CHUNK + t * SCAN_PER_T;
    int c0 = (base     < N_NODES) ? counts[base]     : 0;
    int c1 = (base + 1 < N_NODES) ? counts[base + 1] : 0;
    int s = c0 + c1;
    sdata[t] = s;
    __syncthreads();
    for (int off = 1; off < SCAN_T; off <<= 1) {
        int u = (t >= off) ? sdata[t - off] : 0;
        __syncthreads();
        sdata[t] += u;
        __syncthreads();
    }
    int pre = block_offs[b] + sdata[t] - s;  // exclusive prefix for this thread's pair
    if (base < N_NODES)     { row_ptr[base]     = pre;      cursor[base]     = pre; }
    if (base + 1 < N_NODES) { row_ptr[base + 1] = pre + c0; cursor[base + 1] = pre + c0; }
}

// Scatter edges into dst-sorted (src, weight) records.
__global__ void bucket_kernel(const float* __restrict__ w,
                              const int*   __restrict__ src,
                              const int*   __restrict__ dst,
                              int*         __restrict__ cursor,
                              int2*        __restrict__ recs) {
    int e = blockIdx.x * blockDim.x + threadIdx.x;
    if (e < N_EDGES) {
        int d = dst[e];
        int pos = atomicAdd(&cursor[d], 1);
        recs[pos] = make_int2(src[e], __float_as_int(w[e]));
    }
}

// ---------------- SpMM gather (atomic-free) ----------------
// 4 lanes per node; lane l owns float4 slots {l, 4+l, 8+l} of the 12-float4 row.
__global__ void spmm_gather_kernel(const float* __restrict__ xin,
                                   const int2*  __restrict__ recs,
                                   const int*   __restrict__ row_ptr,
                                   float*       __restrict__ out) {
    int tid = blockIdx.x * blockDim.x + threadIdx.x;
    int n = tid >> 2;
    int l = tid & 3;
    if (n >= N_NODES) return;
    int start = row_ptr[n];
    int end   = row_ptr[n + 1];
    float4 a0 = make_float4(0.f, 0.f, 0.f, 0.f);
    float4 a1 = a0, a2 = a0;
    const float4* __restrict__ X = reinterpret_cast<const float4*>(xin);
    for (int e = start; e < end; ++e) {
        int2 r = recs[e];                        // broadcast within 4-lane group
        float we = __int_as_float(r.y);
        const float4* xr = X + (size_t)r.x * (D_FEAT / 4);
        float4 v0 = xr[l], v1 = xr[4 + l], v2 = xr[8 + l];
        a0.x += we * v0.x; a0.y += we * v0.y; a0.z += we * v0.z; a0.w += we * v0.w;
        a1.x += we * v1.x; a1.y += we * v1.y; a1.z += we * v1.z; a1.w += we * v1.w;
        a2.x += we * v2.x; a2.y += we * v2.y; a2.z += we * v2.z; a2.w += we * v2.w;
    }
    float4* orow = reinterpret_cast<float4*>(out + (size_t)n * D_FEAT);
    orow[l] = a0; orow[4 + l] = a1; orow[8 + l] = a2;
}

extern "C" void kernel_launch(void* const* d_in, const int* in_sizes, int n_in,
                              void* d_out, int out_size, void* d_ws, size_t ws_size,
                              hipStream_t stream) {
    const float* x    = (const float*)d_in[0];
    const float* ew   = (const float*)d_in[1];
    const int*   esrc = (const int*)d_in[2];
    const int*   edst = (const int*)d_in[3];
    float* out = (float*)d_out;

    // Workspace layout (16B-aligned chunks)
    char* ws = (char*)d_ws;
    float* tmp     = (float*)ws;                            // 19,200,000 B
    ws += (size_t)N_NODES * D_FEAT * sizeof(float);
    int2* recs     = (int2*)ws;                             // 12,800,000 B
    ws += (size_t)N_EDGES * sizeof(int2);
    int* row_ptr   = (int*)ws;
    ws += ((size_t)(N_NODES + 1) * sizeof(int) + 15) & ~15ull;
    int* cursor    = (int*)ws;
    ws += ((size_t)N_NODES * sizeof(int) + 15) & ~15ull;
    int* counts    = (int*)ws;
    ws += ((size_t)N_NODES * sizeof(int) + 15) & ~15ull;
    int* block_sums = (int*)ws;
    ws += ((size_t)SCAN_NB * sizeof(int) + 15) & ~15ull;
    int* block_offs = (int*)ws;

    dim3 blk(256);
    dim3 grid_edges((N_EDGES + 255) / 256);
    dim3 grid_nodes(((size_t)N_NODES * 4 + 255) / 256);

    // CSR build (shared by both passes)
    hipMemsetAsync(counts, 0, (size_t)N_NODES * sizeof(int), stream);
    hist_kernel<<<grid_edges, blk, 0, stream>>>(edst, counts);
    scan_partial_kernel<<<SCAN_NB, SCAN_T, 0, stream>>>(counts, block_sums);
    scan_blocksums_kernel<<<1, SCAN_T, 0, stream>>>(block_sums, block_offs, row_ptr);
    scan_write_kernel<<<SCAN_NB, SCAN_T, 0, stream>>>(counts, block_offs, row_ptr, cursor);
    bucket_kernel<<<grid_edges, blk, 0, stream>>>(ew, esrc, edst, cursor, recs);

    // Pass 1: tmp = A @ x ; Pass 2: out = A @ tmp
    spmm_gather_kernel<<<grid_nodes, blk, 0, stream>>>(x,   recs, row_ptr, tmp);
    spmm_gather_kernel<<<grid_nodes, blk, 0, stream>>>(tmp, recs, row_ptr, out);
}

// Round 5
// 305.282 us; speedup vs baseline: 26.1864x; 1.3066x over previous
//
#include <hip/hip_runtime.h>

#define N_NODES 100000
#define N_EDGES 1600000
#define D_FEAT  48

#define BKT_SHIFT 9                                   // 512 nodes per coarse bucket
#define BKT_NODES (1 << BKT_SHIFT)
#define NBKT ((N_NODES + BKT_NODES - 1) / BKT_NODES)  // 196
#define EPB1 2048                                     // edges per phase-1 block
#define NB1  ((N_EDGES + EPB1 - 1) / EPB1)            // 782

// ---------- CSR build: two-level counting sort ----------

// Coarse histogram, LDS-aggregated.
__global__ void hist1_kernel(const int* __restrict__ dst, int* __restrict__ ccount) {
    __shared__ int cnt[NBKT];
    for (int i = threadIdx.x; i < NBKT; i += blockDim.x) cnt[i] = 0;
    __syncthreads();
    int stride = gridDim.x * blockDim.x;
    for (int e = blockIdx.x * blockDim.x + threadIdx.x; e < N_EDGES; e += stride)
        atomicAdd(&cnt[dst[e] >> BKT_SHIFT], 1);
    __syncthreads();
    for (int i = threadIdx.x; i < NBKT; i += blockDim.x)
        if (cnt[i]) atomicAdd(&ccount[i], cnt[i]);
}

// Scan 196 coarse counts -> bucket bases + global cursors.
__global__ void scan196_kernel(const int* __restrict__ ccount,
                               int* __restrict__ bbase,
                               int* __restrict__ cursor,
                               int* __restrict__ row_ptr) {
    __shared__ int sdata[256];
    int t = threadIdx.x;
    int v = (t < NBKT) ? ccount[t] : 0;
    sdata[t] = v;
    __syncthreads();
    for (int off = 1; off < 256; off <<= 1) {
        int u = (t >= off) ? sdata[t - off] : 0;
        __syncthreads();
        sdata[t] += u;
        __syncthreads();
    }
    if (t < NBKT) { int ex = sdata[t] - v; bbase[t] = ex; cursor[t] = ex; }
    if (t == 0)   { bbase[NBKT] = N_EDGES; row_ptr[N_NODES] = N_EDGES; }
}

// Phase 1: scatter edges into coarse buckets (block-aggregated reservation).
// coarse.x = dst_local(9b) | src<<9 ; coarse.y = w bits.
__global__ void p1_kernel(const float* __restrict__ w,
                          const int*   __restrict__ src,
                          const int*   __restrict__ dst,
                          int*         __restrict__ cursor,
                          uint2*       __restrict__ coarse) {
    __shared__ uint2 stage[EPB1];
    __shared__ unsigned char sbkt[EPB1];
    __shared__ int cnt[NBKT], base[NBKT];
    for (int i = threadIdx.x; i < NBKT; i += blockDim.x) cnt[i] = 0;
    __syncthreads();
    int e0 = blockIdx.x * EPB1;
    int n = N_EDGES - e0; if (n > EPB1) n = EPB1;
    for (int i = threadIdx.x; i < n; i += blockDim.x) {
        int e = e0 + i;
        int d = dst[e];
        int b = d >> BKT_SHIFT;
        atomicAdd(&cnt[b], 1);
        stage[i] = make_uint2((unsigned)(d & (BKT_NODES - 1)) | ((unsigned)src[e] << BKT_SHIFT),
                              (unsigned)__float_as_uint(w[e]));
        sbkt[i] = (unsigned char)b;
    }
    __syncthreads();
    for (int i = threadIdx.x; i < NBKT; i += blockDim.x) {
        int c = cnt[i];
        base[i] = c ? atomicAdd(&cursor[i], c) : 0;
        cnt[i] = 0;  // reuse as local cursor
    }
    __syncthreads();
    for (int i = threadIdx.x; i < n; i += blockDim.x) {
        int b = sbkt[i];
        int pos = base[b] + atomicAdd(&cnt[b], 1);
        coarse[pos] = stage[i];
    }
}

// Phase 2: one block per coarse bucket -> fine sort + row_ptr.
__global__ void p2_kernel(const uint2* __restrict__ coarse,
                          const int*   __restrict__ bbase,
                          int2*        __restrict__ recs,
                          int*         __restrict__ row_ptr) {
    __shared__ int cnt[BKT_NODES];   // per-node counts, then cursors
    __shared__ int ssum[256];
    int b = blockIdx.x, t = threadIdx.x;
    int lo = bbase[b], hi = bbase[b + 1];
    cnt[2 * t] = 0; cnt[2 * t + 1] = 0;
    __syncthreads();
    for (int i = lo + t; i < hi; i += 256)
        atomicAdd(&cnt[coarse[i].x & (BKT_NODES - 1)], 1);
    __syncthreads();
    int c0 = cnt[2 * t], c1 = cnt[2 * t + 1];
    int s = c0 + c1;
    ssum[t] = s;
    __syncthreads();
    for (int off = 1; off < 256; off <<= 1) {
        int u = (t >= off) ? ssum[t - off] : 0;
        __syncthreads();
        ssum[t] += u;
        __syncthreads();
    }
    int pre = lo + ssum[t] - s;  // global exclusive prefix for node 2t
    int node0 = (b << BKT_SHIFT);
    cnt[2 * t] = pre;
    cnt[2 * t + 1] = pre + c0;
    if (node0 + 2 * t     < N_NODES) row_ptr[node0 + 2 * t]     = pre;
    if (node0 + 2 * t + 1 < N_NODES) row_ptr[node0 + 2 * t + 1] = pre + c0;
    __syncthreads();
    for (int i = lo + t; i < hi; i += 256) {
        uint2 r = coarse[i];
        int pos = atomicAdd(&cnt[r.x & (BKT_NODES - 1)], 1);
        recs[pos] = make_int2((int)(r.x >> BKT_SHIFT), (int)r.y);
    }
}

// ---------- SpMM gather (atomic-free) ----------
// 4 lanes per node; lane l owns float4 slots {l, 4+l, 8+l}.
__global__ void spmm_gather_kernel(const float* __restrict__ xin,
                                   const int2*  __restrict__ recs,
                                   const int*   __restrict__ row_ptr,
                                   float*       __restrict__ out) {
    int tid = blockIdx.x * blockDim.x + threadIdx.x;
    int n = tid >> 2;
    int l = tid & 3;
    if (n >= N_NODES) return;
    int start = row_ptr[n];
    int end   = row_ptr[n + 1];
    float4 a0 = make_float4(0.f, 0.f, 0.f, 0.f);
    float4 a1 = a0, a2 = a0;
    const float4* __restrict__ X = reinterpret_cast<const float4*>(xin);
    for (int e = start; e < end; ++e) {
        int2 r = recs[e];
        float we = __int_as_float(r.y);
        const float4* xr = X + (size_t)r.x * (D_FEAT / 4);
        float4 v0 = xr[l], v1 = xr[4 + l], v2 = xr[8 + l];
        a0.x += we * v0.x; a0.y += we * v0.y; a0.z += we * v0.z; a0.w += we * v0.w;
        a1.x += we * v1.x; a1.y += we * v1.y; a1.z += we * v1.z; a1.w += we * v1.w;
        a2.x += we * v2.x; a2.y += we * v2.y; a2.z += we * v2.z; a2.w += we * v2.w;
    }
    float4* orow = reinterpret_cast<float4*>(out + (size_t)n * D_FEAT);
    orow[l] = a0; orow[4 + l] = a1; orow[8 + l] = a2;
}

extern "C" void kernel_launch(void* const* d_in, const int* in_sizes, int n_in,
                              void* d_out, int out_size, void* d_ws, size_t ws_size,
                              hipStream_t stream) {
    const float* x    = (const float*)d_in[0];
    const float* ew   = (const float*)d_in[1];
    const int*   esrc = (const int*)d_in[2];
    const int*   edst = (const int*)d_in[3];
    float* out = (float*)d_out;

    // Workspace layout. coarse aliases tmp (tmp unused until spmm pass 1,
    // which runs after p2 has consumed coarse).
    char* ws = (char*)d_ws;
    float* tmp   = (float*)ws;                      // 19.2 MB (>= 12.8 MB for coarse)
    uint2* coarse = (uint2*)ws;
    ws += (size_t)N_NODES * D_FEAT * sizeof(float);
    int2* recs   = (int2*)ws;                       // 12.8 MB
    ws += (size_t)N_EDGES * sizeof(int2);
    int* row_ptr = (int*)ws;
    ws += ((size_t)(N_NODES + 1) * sizeof(int) + 15) & ~15ull;
    int* ccount  = (int*)ws;
    ws += ((size_t)NBKT * sizeof(int) + 15) & ~15ull;
    int* bbase   = (int*)ws;
    ws += ((size_t)(NBKT + 1) * sizeof(int) + 15) & ~15ull;
    int* cursor  = (int*)ws;

    dim3 blk(256);
    dim3 grid_nodes(((size_t)N_NODES * 4 + 255) / 256);

    // CSR build
    hipMemsetAsync(ccount, 0, NBKT * sizeof(int), stream);
    hist1_kernel<<<1024, blk, 0, stream>>>(edst, ccount);
    scan196_kernel<<<1, blk, 0, stream>>>(ccount, bbase, cursor, row_ptr);
    p1_kernel<<<NB1, blk, 0, stream>>>(ew, esrc, edst, cursor, coarse);
    p2_kernel<<<NBKT, blk, 0, stream>>>(coarse, bbase, recs, row_ptr);

    // Pass 1: tmp = A @ x ; Pass 2: out = A @ tmp
    spmm_gather_kernel<<<grid_nodes, blk, 0, stream>>>(x,   recs, row_ptr, tmp);
    spmm_gather_kernel<<<grid_nodes, blk, 0, stream>>>(tmp, recs, row_ptr, out);
}

// Round 7
// 258.669 us; speedup vs baseline: 30.9053x; 1.1802x over previous
//
#include <hip/hip_runtime.h>

#define N_NODES 100000
#define N_EDGES 1600000
#define D_FEAT  48

#define BKT_SHIFT 9                                   // 512 nodes per coarse bucket
#define BKT_NODES (1 << BKT_SHIFT)
#define NBKT ((N_NODES + BKT_NODES - 1) / BKT_NODES)  // 196
#define EPB1 2048                                     // edges per phase-1 block
#define NB1  ((N_EDGES + EPB1 - 1) / EPB1)            // 782

__device__ __forceinline__ unsigned short bf16_rn(float f) {
    unsigned u = __float_as_uint(f);
    unsigned r = (u + 0x7fffu + ((u >> 16) & 1u)) >> 16;
    return (unsigned short)r;
}
__device__ __forceinline__ float bf2f(unsigned short b) {
    return __uint_as_float(((unsigned)b) << 16);
}

// ---------- x (f32) -> xb (bf16) ----------
__global__ void cvt_bf16_kernel(const float* __restrict__ in,
                                unsigned short* __restrict__ outb, int n4) {
    int i = blockIdx.x * blockDim.x + threadIdx.x;
    int stride = gridDim.x * blockDim.x;
    const float4* in4 = (const float4*)in;
    ushort4* o4 = (ushort4*)outb;
    for (; i < n4; i += stride) {
        float4 v = in4[i];
        ushort4 o;
        o.x = bf16_rn(v.x); o.y = bf16_rn(v.y);
        o.z = bf16_rn(v.z); o.w = bf16_rn(v.w);
        o4[i] = o;
    }
}

// ---------- CSR build: two-level counting sort ----------

__global__ void hist1_kernel(const int* __restrict__ dst, int* __restrict__ ccount) {
    __shared__ int cnt[NBKT];
    for (int i = threadIdx.x; i < NBKT; i += blockDim.x) cnt[i] = 0;
    __syncthreads();
    int stride = gridDim.x * blockDim.x;
    for (int e = blockIdx.x * blockDim.x + threadIdx.x; e < N_EDGES; e += stride)
        atomicAdd(&cnt[dst[e] >> BKT_SHIFT], 1);
    __syncthreads();
    for (int i = threadIdx.x; i < NBKT; i += blockDim.x)
        if (cnt[i]) atomicAdd(&ccount[i], cnt[i]);
}

__global__ void scan196_kernel(const int* __restrict__ ccount,
                               int* __restrict__ bbase,
                               int* __restrict__ cursor,
                               int* __restrict__ row_ptr) {
    __shared__ int sdata[256];
    int t = threadIdx.x;
    int v = (t < NBKT) ? ccount[t] : 0;
    sdata[t] = v;
    __syncthreads();
    for (int off = 1; off < 256; off <<= 1) {
        int u = (t >= off) ? sdata[t - off] : 0;
        __syncthreads();
        sdata[t] += u;
        __syncthreads();
    }
    if (t < NBKT) { int ex = sdata[t] - v; bbase[t] = ex; cursor[t] = ex; }
    if (t == 0)   { bbase[NBKT] = N_EDGES; row_ptr[N_NODES] = N_EDGES; }
}

// coarse.x = dst_local(9b) | src<<9 ; coarse.y = w bits.
__global__ void p1_kernel(const float* __restrict__ w,
                          const int*   __restrict__ src,
                          const int*   __restrict__ dst,
                          int*         __restrict__ cursor,
                          uint2*       __restrict__ coarse) {
    __shared__ uint2 stage[EPB1];
    __shared__ unsigned char sbkt[EPB1];
    __shared__ int cnt[NBKT], base[NBKT];
    for (int i = threadIdx.x; i < NBKT; i += blockDim.x) cnt[i] = 0;
    __syncthreads();
    int e0 = blockIdx.x * EPB1;
    int n = N_EDGES - e0; if (n > EPB1) n = EPB1;
    for (int i = threadIdx.x; i < n; i += blockDim.x) {
        int e = e0 + i;
        int d = dst[e];
        int b = d >> BKT_SHIFT;
        atomicAdd(&cnt[b], 1);
        stage[i] = make_uint2((unsigned)(d & (BKT_NODES - 1)) | ((unsigned)src[e] << BKT_SHIFT),
                              (unsigned)__float_as_uint(w[e]));
        sbkt[i] = (unsigned char)b;
    }
    __syncthreads();
    for (int i = threadIdx.x; i < NBKT; i += blockDim.x) {
        int c = cnt[i];
        base[i] = c ? atomicAdd(&cursor[i], c) : 0;
        cnt[i] = 0;  // reuse as local cursor
    }
    __syncthreads();
    for (int i = threadIdx.x; i < n; i += blockDim.x) {
        int b = sbkt[i];
        int pos = base[b] + atomicAdd(&cnt[b], 1);
        coarse[pos] = stage[i];
    }
}

__global__ void p2_kernel(const uint2* __restrict__ coarse,
                          const int*   __restrict__ bbase,
                          int2*        __restrict__ recs,
                          int*         __restrict__ row_ptr) {
    __shared__ int cnt[BKT_NODES];
    __shared__ int ssum[256];
    int b = blockIdx.x, t = threadIdx.x;
    int lo = bbase[b], hi = bbase[b + 1];
    cnt[2 * t] = 0; cnt[2 * t + 1] = 0;
    __syncthreads();
    for (int i = lo + t; i < hi; i += 256)
        atomicAdd(&cnt[coarse[i].x & (BKT_NODES - 1)], 1);
    __syncthreads();
    int c0 = cnt[2 * t], c1 = cnt[2 * t + 1];
    int s = c0 + c1;
    ssum[t] = s;
    __syncthreads();
    for (int off = 1; off < 256; off <<= 1) {
        int u = (t >= off) ? ssum[t - off] : 0;
        __syncthreads();
        ssum[t] += u;
        __syncthreads();
    }
    int pre = lo + ssum[t] - s;
    int node0 = (b << BKT_SHIFT);
    cnt[2 * t] = pre;
    cnt[2 * t + 1] = pre + c0;
    if (node0 + 2 * t     < N_NODES) row_ptr[node0 + 2 * t]     = pre;
    if (node0 + 2 * t + 1 < N_NODES) row_ptr[node0 + 2 * t + 1] = pre + c0;
    __syncthreads();
    for (int i = lo + t; i < hi; i += 256) {
        uint2 r = coarse[i];
        int pos = atomicAdd(&cnt[r.x & (BKT_NODES - 1)], 1);
        recs[pos] = make_int2((int)(r.x >> BKT_SHIFT), (int)r.y);
    }
}

// ---------- SpMM gather (bf16 features, f32 accumulate) ----------
// 4 lanes per node; row = 12 slots of 4 bf16 (8B); lane l owns slots {l, 4+l, 8+l}.
__device__ __forceinline__ void acc4(float* a, ushort4 u, float w) {
    a[0] += w * bf2f(u.x);
    a[1] += w * bf2f(u.y);
    a[2] += w * bf2f(u.z);
    a[3] += w * bf2f(u.w);
}

template <bool OUT_BF16>
__global__ void spmm_gather_b_kernel(const unsigned short* __restrict__ xb,
                                     const int2* __restrict__ recs,
                                     const int*  __restrict__ row_ptr,
                                     void* __restrict__ outv) {
    int tid = blockIdx.x * blockDim.x + threadIdx.x;
    int n = tid >> 2;
    int l = tid & 3;
    if (n >= N_NODES) return;
    int e   = row_ptr[n];
    int end = row_ptr[n + 1];
    float a0[4] = {0.f, 0.f, 0.f, 0.f};
    float a1[4] = {0.f, 0.f, 0.f, 0.f};
    float a2[4] = {0.f, 0.f, 0.f, 0.f};
    const ushort4* __restrict__ X = reinterpret_cast<const ushort4*>(xb);
    for (; e + 1 < end; e += 2) {
        int2 r0 = recs[e];
        int2 r1 = recs[e + 1];
        float w0 = __int_as_float(r0.y);
        float w1 = __int_as_float(r1.y);
        const ushort4* x0 = X + (size_t)r0.x * (D_FEAT / 4);
        const ushort4* x1 = X + (size_t)r1.x * (D_FEAT / 4);
        ushort4 u00 = x0[l], u01 = x0[4 + l], u02 = x0[8 + l];
        ushort4 u10 = x1[l], u11 = x1[4 + l], u12 = x1[8 + l];
        acc4(a0, u00, w0); acc4(a1, u01, w0); acc4(a2, u02, w0);
        acc4(a0, u10, w1); acc4(a1, u11, w1); acc4(a2, u12, w1);
    }
    if (e < end) {
        int2 r = recs[e];
        float we = __int_as_float(r.y);
        const ushort4* xr = X + (size_t)r.x * (D_FEAT / 4);
        acc4(a0, xr[l], we); acc4(a1, xr[4 + l], we); acc4(a2, xr[8 + l], we);
    }
    if (OUT_BF16) {
        ushort4* orow = reinterpret_cast<ushort4*>((unsigned short*)outv + (size_t)n * D_FEAT);
        ushort4 o0, o1, o2;
        o0.x = bf16_rn(a0[0]); o0.y = bf16_rn(a0[1]); o0.z = bf16_rn(a0[2]); o0.w = bf16_rn(a0[3]);
        o1.x = bf16_rn(a1[0]); o1.y = bf16_rn(a1[1]); o1.z = bf16_rn(a1[2]); o1.w = bf16_rn(a1[3]);
        o2.x = bf16_rn(a2[0]); o2.y = bf16_rn(a2[1]); o2.z = bf16_rn(a2[2]); o2.w = bf16_rn(a2[3]);
        orow[l] = o0; orow[4 + l] = o1; orow[8 + l] = o2;
    } else {
        float4* orow = reinterpret_cast<float4*>((float*)outv + (size_t)n * D_FEAT);
        orow[l]     = make_float4(a0[0], a0[1], a0[2], a0[3]);
        orow[4 + l] = make_float4(a1[0], a1[1], a1[2], a1[3]);
        orow[8 + l] = make_float4(a2[0], a2[1], a2[2], a2[3]);
    }
}

extern "C" void kernel_launch(void* const* d_in, const int* in_sizes, int n_in,
                              void* d_out, int out_size, void* d_ws, size_t ws_size,
                              hipStream_t stream) {
    const float* x    = (const float*)d_in[0];
    const float* ew   = (const float*)d_in[1];
    const int*   esrc = (const int*)d_in[2];
    const int*   edst = (const int*)d_in[3];
    float* out = (float*)d_out;

    // Workspace layout. tmpb (bf16 plane, 9.6 MB) shares its 12.8 MB slot with
    // coarse: p2 consumes coarse before spmm pass 1 writes tmpb (stream-ordered).
    char* ws = (char*)d_ws;
    unsigned short* xb = (unsigned short*)ws;                 // 9.6 MB
    ws += (((size_t)N_NODES * D_FEAT * sizeof(unsigned short)) + 15) & ~15ull;
    unsigned short* tmpb = (unsigned short*)ws;               // 12.8 MB (max of tmpb/coarse)
    uint2* coarse = (uint2*)ws;
    ws += (size_t)N_EDGES * sizeof(uint2);
    int2* recs = (int2*)ws;                                   // 12.8 MB
    ws += (size_t)N_EDGES * sizeof(int2);
    int* row_ptr = (int*)ws;
    ws += ((size_t)(N_NODES + 1) * sizeof(int) + 15) & ~15ull;
    int* ccount = (int*)ws;
    ws += ((size_t)NBKT * sizeof(int) + 15) & ~15ull;
    int* bbase = (int*)ws;
    ws += ((size_t)(NBKT + 1) * sizeof(int) + 15) & ~15ull;
    int* cursor = (int*)ws;

    dim3 blk(256);
    dim3 grid_nodes(((size_t)N_NODES * 4 + 255) / 256);

    // CSR build + bf16 conversion
    hipMemsetAsync(ccount, 0, NBKT * sizeof(int), stream);
    cvt_bf16_kernel<<<1024, blk, 0, stream>>>(x, xb, (N_NODES * D_FEAT) / 4);
    hist1_kernel<<<1024, blk, 0, stream>>>(edst, ccount);
    scan196_kernel<<<1, blk, 0, stream>>>(ccount, bbase, cursor, row_ptr);
    p1_kernel<<<NB1, blk, 0, stream>>>(ew, esrc, edst, cursor, coarse);
    p2_kernel<<<NBKT, blk, 0, stream>>>(coarse, bbase, recs, row_ptr);

    // Pass 1: tmpb = bf16(A @ xb) ; Pass 2: out = A @ tmpb (f32 out)
    spmm_gather_b_kernel<true><<<grid_nodes, blk, 0, stream>>>(xb, recs, row_ptr, tmpb);
    spmm_gather_b_kernel<false><<<grid_nodes, blk, 0, stream>>>(tmpb, recs, row_ptr, out);
}

// Round 8
// 244.780 us; speedup vs baseline: 32.6589x; 1.0567x over previous
//
#include <hip/hip_runtime.h>

#define N_NODES 100000
#define N_EDGES 1600000
#define D_FEAT  48

#define BKT_SHIFT 9                                   // 512 nodes per coarse bucket
#define BKT_NODES (1 << BKT_SHIFT)
#define NBKT ((N_NODES + BKT_NODES - 1) / BKT_NODES)  // 196
#define EPB1 2048                                     // edges per phase-1 block
#define NB1  ((N_EDGES + EPB1 - 1) / EPB1)            // 782
#define P2_CAP 9216                                   // LDS-staged edges (avg 8163, +11 sigma)

__device__ __forceinline__ unsigned short bf16_rn(float f) {
    unsigned u = __float_as_uint(f);
    unsigned r = (u + 0x7fffu + ((u >> 16) & 1u)) >> 16;
    return (unsigned short)r;
}
__device__ __forceinline__ float bf2f(unsigned short b) {
    return __uint_as_float(((unsigned)b) << 16);
}

// ---------- fused: x(f32)->xb(bf16)  +  coarse histogram ----------
__global__ void cvt_hist_kernel(const float* __restrict__ in,
                                unsigned short* __restrict__ outb,
                                const int* __restrict__ dst,
                                int* __restrict__ ccount) {
    __shared__ int cnt[NBKT];
    for (int i = threadIdx.x; i < NBKT; i += blockDim.x) cnt[i] = 0;
    __syncthreads();
    int tid = blockIdx.x * blockDim.x + threadIdx.x;
    int stride = gridDim.x * blockDim.x;
    const float4* in4 = (const float4*)in;
    ushort4* o4 = (ushort4*)outb;
    const int n4 = (N_NODES * D_FEAT) / 4;
    for (int i = tid; i < n4; i += stride) {
        float4 v = in4[i];
        ushort4 o;
        o.x = bf16_rn(v.x); o.y = bf16_rn(v.y);
        o.z = bf16_rn(v.z); o.w = bf16_rn(v.w);
        o4[i] = o;
    }
    for (int e = tid; e < N_EDGES; e += stride)
        atomicAdd(&cnt[dst[e] >> BKT_SHIFT], 1);
    __syncthreads();
    for (int i = threadIdx.x; i < NBKT; i += blockDim.x)
        if (cnt[i]) atomicAdd(&ccount[i], cnt[i]);
}

__global__ void scan196_kernel(const int* __restrict__ ccount,
                               int* __restrict__ bbase,
                               int* __restrict__ cursor,
                               int* __restrict__ row_ptr) {
    __shared__ int sdata[256];
    int t = threadIdx.x;
    int v = (t < NBKT) ? ccount[t] : 0;
    sdata[t] = v;
    __syncthreads();
    for (int off = 1; off < 256; off <<= 1) {
        int u = (t >= off) ? sdata[t - off] : 0;
        __syncthreads();
        sdata[t] += u;
        __syncthreads();
    }
    if (t < NBKT) { int ex = sdata[t] - v; bbase[t] = ex; cursor[t] = ex; }
    if (t == 0)   { bbase[NBKT] = N_EDGES; row_ptr[N_NODES] = N_EDGES; }
}

// coarse.x = dst_local(9b) | src<<9 ; coarse.y = w bits.
__global__ void p1_kernel(const float* __restrict__ w,
                          const int*   __restrict__ src,
                          const int*   __restrict__ dst,
                          int*         __restrict__ cursor,
                          uint2*       __restrict__ coarse) {
    __shared__ uint2 stage[EPB1];
    __shared__ unsigned char sbkt[EPB1];
    __shared__ int cnt[NBKT], base[NBKT];
    for (int i = threadIdx.x; i < NBKT; i += blockDim.x) cnt[i] = 0;
    __syncthreads();
    int e0 = blockIdx.x * EPB1;
    int n = N_EDGES - e0; if (n > EPB1) n = EPB1;
    for (int i = threadIdx.x; i < n; i += blockDim.x) {
        int e = e0 + i;
        int d = dst[e];
        int b = d >> BKT_SHIFT;
        atomicAdd(&cnt[b], 1);
        stage[i] = make_uint2((unsigned)(d & (BKT_NODES - 1)) | ((unsigned)src[e] << BKT_SHIFT),
                              (unsigned)__float_as_uint(w[e]));
        sbkt[i] = (unsigned char)b;
    }
    __syncthreads();
    for (int i = threadIdx.x; i < NBKT; i += blockDim.x) {
        int c = cnt[i];
        base[i] = c ? atomicAdd(&cursor[i], c) : 0;
        cnt[i] = 0;  // reuse as local cursor
    }
    __syncthreads();
    for (int i = threadIdx.x; i < n; i += blockDim.x) {
        int b = sbkt[i];
        int pos = base[b] + atomicAdd(&cnt[b], 1);
        coarse[pos] = stage[i];
    }
}

// Phase 2: one block per coarse bucket; edges staged once in LDS.
__global__ __launch_bounds__(512) void p2_kernel(const uint2* __restrict__ coarse,
                                                 const int*   __restrict__ bbase,
                                                 int2*        __restrict__ recs,
                                                 int*         __restrict__ row_ptr) {
    __shared__ uint2 sedge[P2_CAP];     // 72 KB
    __shared__ int cnt[BKT_NODES];      // 2 KB
    __shared__ int ssum[512];           // 2 KB
    int b = blockIdx.x, t = threadIdx.x;
    int lo = bbase[b], hi = bbase[b + 1];
    int m = hi - lo;
    int staged = (m < P2_CAP) ? m : P2_CAP;
    for (int i = t; i < staged; i += 512) sedge[i] = coarse[lo + i];
    cnt[t] = 0;                          // BKT_NODES == 512 == blockDim
    __syncthreads();
    for (int i = t; i < m; i += 512) {
        uint2 r = (i < staged) ? sedge[i] : coarse[lo + i];
        atomicAdd(&cnt[r.x & (BKT_NODES - 1)], 1);
    }
    __syncthreads();
    int c = cnt[t];
    ssum[t] = c;
    __syncthreads();
    for (int off = 1; off < 512; off <<= 1) {
        int u = (t >= off) ? ssum[t - off] : 0;
        __syncthreads();
        ssum[t] += u;
        __syncthreads();
    }
    int pre = lo + ssum[t] - c;          // global exclusive prefix for node (b<<9)+t
    int node = (b << BKT_SHIFT) + t;
    if (node < N_NODES) row_ptr[node] = pre;
    cnt[t] = pre;                        // becomes cursor
    __syncthreads();
    for (int i = t; i < m; i += 512) {
        uint2 r = (i < staged) ? sedge[i] : coarse[lo + i];
        int pos = atomicAdd(&cnt[r.x & (BKT_NODES - 1)], 1);
        recs[pos] = make_int2((int)(r.x >> BKT_SHIFT), (int)r.y);
    }
}

// ---------- SpMM gather (bf16 features, f32 accumulate, unroll 4) ----------
__device__ __forceinline__ void acc4(float* a, ushort4 u, float w) {
    a[0] += w * bf2f(u.x);
    a[1] += w * bf2f(u.y);
    a[2] += w * bf2f(u.z);
    a[3] += w * bf2f(u.w);
}

template <bool OUT_BF16>
__global__ void spmm_gather_b_kernel(const unsigned short* __restrict__ xb,
                                     const int2* __restrict__ recs,
                                     const int*  __restrict__ row_ptr,
                                     void* __restrict__ outv) {
    int tid = blockIdx.x * blockDim.x + threadIdx.x;
    int n = tid >> 2;
    int l = tid & 3;
    if (n >= N_NODES) return;
    int e   = row_ptr[n];
    int end = row_ptr[n + 1];
    float a0[4] = {0.f, 0.f, 0.f, 0.f};
    float a1[4] = {0.f, 0.f, 0.f, 0.f};
    float a2[4] = {0.f, 0.f, 0.f, 0.f};
    const ushort4* __restrict__ X = reinterpret_cast<const ushort4*>(xb);
    for (; e + 3 < end; e += 4) {
        int2 r0 = recs[e],     r1 = recs[e + 1];
        int2 r2 = recs[e + 2], r3 = recs[e + 3];
        const ushort4* x0 = X + (size_t)r0.x * (D_FEAT / 4);
        const ushort4* x1 = X + (size_t)r1.x * (D_FEAT / 4);
        const ushort4* x2 = X + (size_t)r2.x * (D_FEAT / 4);
        const ushort4* x3 = X + (size_t)r3.x * (D_FEAT / 4);
        ushort4 u00 = x0[l], u01 = x0[4 + l], u02 = x0[8 + l];
        ushort4 u10 = x1[l], u11 = x1[4 + l], u12 = x1[8 + l];
        ushort4 u20 = x2[l], u21 = x2[4 + l], u22 = x2[8 + l];
        ushort4 u30 = x3[l], u31 = x3[4 + l], u32 = x3[8 + l];
        float w0 = __int_as_float(r0.y), w1 = __int_as_float(r1.y);
        float w2 = __int_as_float(r2.y), w3 = __int_as_float(r3.y);
        acc4(a0, u00, w0); acc4(a1, u01, w0); acc4(a2, u02, w0);
        acc4(a0, u10, w1); acc4(a1, u11, w1); acc4(a2, u12, w1);
        acc4(a0, u20, w2); acc4(a1, u21, w2); acc4(a2, u22, w2);
        acc4(a0, u30, w3); acc4(a1, u31, w3); acc4(a2, u32, w3);
    }
    for (; e < end; ++e) {
        int2 r = recs[e];
        float we = __int_as_float(r.y);
        const ushort4* xr = X + (size_t)r.x * (D_FEAT / 4);
        acc4(a0, xr[l], we); acc4(a1, xr[4 + l], we); acc4(a2, xr[8 + l], we);
    }
    if (OUT_BF16) {
        ushort4* orow = reinterpret_cast<ushort4*>((unsigned short*)outv + (size_t)n * D_FEAT);
        ushort4 o0, o1, o2;
        o0.x = bf16_rn(a0[0]); o0.y = bf16_rn(a0[1]); o0.z = bf16_rn(a0[2]); o0.w = bf16_rn(a0[3]);
        o1.x = bf16_rn(a1[0]); o1.y = bf16_rn(a1[1]); o1.z = bf16_rn(a1[2]); o1.w = bf16_rn(a1[3]);
        o2.x = bf16_rn(a2[0]); o2.y = bf16_rn(a2[1]); o2.z = bf16_rn(a2[2]); o2.w = bf16_rn(a2[3]);
        orow[l] = o0; orow[4 + l] = o1; orow[8 + l] = o2;
    } else {
        float4* orow = reinterpret_cast<float4*>((float*)outv + (size_t)n * D_FEAT);
        orow[l]     = make_float4(a0[0], a0[1], a0[2], a0[3]);
        orow[4 + l] = make_float4(a1[0], a1[1], a1[2], a1[3]);
        orow[8 + l] = make_float4(a2[0], a2[1], a2[2], a2[3]);
    }
}

extern "C" void kernel_launch(void* const* d_in, const int* in_sizes, int n_in,
                              void* d_out, int out_size, void* d_ws, size_t ws_size,
                              hipStream_t stream) {
    const float* x    = (const float*)d_in[0];
    const float* ew   = (const float*)d_in[1];
    const int*   esrc = (const int*)d_in[2];
    const int*   edst = (const int*)d_in[3];
    float* out = (float*)d_out;

    // Workspace layout. tmpb (bf16, 9.6 MB) shares its slot with coarse
    // (12.8 MB): p2 consumes coarse before spmm pass 1 writes tmpb.
    char* ws = (char*)d_ws;
    unsigned short* xb = (unsigned short*)ws;                 // 9.6 MB
    ws += (((size_t)N_NODES * D_FEAT * sizeof(unsigned short)) + 15) & ~15ull;
    unsigned short* tmpb = (unsigned short*)ws;
    uint2* coarse = (uint2*)ws;
    ws += (size_t)N_EDGES * sizeof(uint2);
    int2* recs = (int2*)ws;                                   // 12.8 MB
    ws += (size_t)N_EDGES * sizeof(int2);
    int* row_ptr = (int*)ws;
    ws += ((size_t)(N_NODES + 1) * sizeof(int) + 15) & ~15ull;
    int* ccount = (int*)ws;
    ws += ((size_t)NBKT * sizeof(int) + 15) & ~15ull;
    int* bbase = (int*)ws;
    ws += ((size_t)(NBKT + 1) * sizeof(int) + 15) & ~15ull;
    int* cursor = (int*)ws;

    dim3 blk(256);
    dim3 grid_nodes(((size_t)N_NODES * 4 + 255) / 256);

    // CSR build + bf16 conversion
    hipMemsetAsync(ccount, 0, NBKT * sizeof(int), stream);
    cvt_hist_kernel<<<1024, blk, 0, stream>>>(x, xb, edst, ccount);
    scan196_kernel<<<1, blk, 0, stream>>>(ccount, bbase, cursor, row_ptr);
    p1_kernel<<<NB1, blk, 0, stream>>>(ew, esrc, edst, cursor, coarse);
    p2_kernel<<<NBKT, dim3(512), 0, stream>>>(coarse, bbase, recs, row_ptr);

    // Pass 1: tmpb = bf16(A @ xb) ; Pass 2: out = A @ tmpb (f32 out)
    spmm_gather_b_kernel<true><<<grid_nodes, blk, 0, stream>>>(xb, recs, row_ptr, tmpb);
    spmm_gather_b_kernel<false><<<grid_nodes, blk, 0, stream>>>(tmpb, recs, row_ptr, out);
}

// Round 9
// 242.290 us; speedup vs baseline: 32.9946x; 1.0103x over previous
//
#include <hip/hip_runtime.h>

#define N_NODES 100000
#define N_EDGES 1600000
#define D_FEAT  48

#define BKT_SHIFT 9                                   // 512 nodes per coarse bucket
#define BKT_NODES (1 << BKT_SHIFT)
#define NBKT ((N_NODES + BKT_NODES - 1) / BKT_NODES)  // 196
#define EPB1 2048                                     // edges per phase-1 block
#define NB1  ((N_EDGES + EPB1 - 1) / EPB1)            // 782
#define P2_CAP 9216                                   // LDS-staged edges (avg 8163)
#define TILE_SHIFT 14                                 // src tile = src>>14 (0..6)
#define NTILE 8
#define KEYS (BKT_NODES * NTILE)                      // 4096

__device__ __forceinline__ unsigned short bf16_rn(float f) {
    unsigned u = __float_as_uint(f);
    unsigned r = (u + 0x7fffu + ((u >> 16) & 1u)) >> 16;
    return (unsigned short)r;
}
__device__ __forceinline__ float bf2f(unsigned short b) {
    return __uint_as_float(((unsigned)b) << 16);
}

// ---------- fused: x(f32)->xb(bf16)  +  coarse histogram ----------
__global__ void cvt_hist_kernel(const float* __restrict__ in,
                                unsigned short* __restrict__ outb,
                                const int* __restrict__ dst,
                                int* __restrict__ ccount) {
    __shared__ int cnt[NBKT];
    for (int i = threadIdx.x; i < NBKT; i += blockDim.x) cnt[i] = 0;
    __syncthreads();
    int tid = blockIdx.x * blockDim.x + threadIdx.x;
    int stride = gridDim.x * blockDim.x;
    const float4* in4 = (const float4*)in;
    ushort4* o4 = (ushort4*)outb;
    const int n4 = (N_NODES * D_FEAT) / 4;
    for (int i = tid; i < n4; i += stride) {
        float4 v = in4[i];
        ushort4 o;
        o.x = bf16_rn(v.x); o.y = bf16_rn(v.y);
        o.z = bf16_rn(v.z); o.w = bf16_rn(v.w);
        o4[i] = o;
    }
    for (int e = tid; e < N_EDGES; e += stride)
        atomicAdd(&cnt[dst[e] >> BKT_SHIFT], 1);
    __syncthreads();
    for (int i = threadIdx.x; i < NBKT; i += blockDim.x)
        if (cnt[i]) atomicAdd(&ccount[i], cnt[i]);
}

__global__ void scan196_kernel(const int* __restrict__ ccount,
                               int* __restrict__ bbase,
                               int* __restrict__ cursor,
                               int* __restrict__ row_ptr) {
    __shared__ int sdata[256];
    int t = threadIdx.x;
    int v = (t < NBKT) ? ccount[t] : 0;
    sdata[t] = v;
    __syncthreads();
    for (int off = 1; off < 256; off <<= 1) {
        int u = (t >= off) ? sdata[t - off] : 0;
        __syncthreads();
        sdata[t] += u;
        __syncthreads();
    }
    if (t < NBKT) { int ex = sdata[t] - v; bbase[t] = ex; cursor[t] = ex; }
    if (t == 0)   { bbase[NBKT] = N_EDGES; row_ptr[N_NODES] = N_EDGES; }
}

// coarse.x = dst_local(9b) | src<<9 ; coarse.y = w bits.
__global__ void p1_kernel(const float* __restrict__ w,
                          const int*   __restrict__ src,
                          const int*   __restrict__ dst,
                          int*         __restrict__ cursor,
                          uint2*       __restrict__ coarse) {
    __shared__ uint2 stage[EPB1];
    __shared__ unsigned char sbkt[EPB1];
    __shared__ int cnt[NBKT], base[NBKT];
    for (int i = threadIdx.x; i < NBKT; i += blockDim.x) cnt[i] = 0;
    __syncthreads();
    int e0 = blockIdx.x * EPB1;
    int n = N_EDGES - e0; if (n > EPB1) n = EPB1;
    for (int i = threadIdx.x; i < n; i += blockDim.x) {
        int e = e0 + i;
        int d = dst[e];
        int b = d >> BKT_SHIFT;
        atomicAdd(&cnt[b], 1);
        stage[i] = make_uint2((unsigned)(d & (BKT_NODES - 1)) | ((unsigned)src[e] << BKT_SHIFT),
                              (unsigned)__float_as_uint(w[e]));
        sbkt[i] = (unsigned char)b;
    }
    __syncthreads();
    for (int i = threadIdx.x; i < NBKT; i += blockDim.x) {
        int c = cnt[i];
        base[i] = c ? atomicAdd(&cursor[i], c) : 0;
        cnt[i] = 0;  // reuse as local cursor
    }
    __syncthreads();
    for (int i = threadIdx.x; i < n; i += blockDim.x) {
        int b = sbkt[i];
        int pos = base[b] + atomicAdd(&cnt[b], 1);
        coarse[pos] = stage[i];
    }
}

// Phase 2: one block per coarse bucket; key = dst_local*8 + src_tile so each
// node's edge list comes out src-tile-sorted (L2 temporal clustering for SpMM).
// Thread t owns keys [8t, 8t+8) == node t's 8 tiles -> row_ptr falls out.
__global__ __launch_bounds__(512) void p2_kernel(const uint2* __restrict__ coarse,
                                                 const int*   __restrict__ bbase,
                                                 int2*        __restrict__ recs,
                                                 int*         __restrict__ row_ptr) {
    __shared__ uint2 sedge[P2_CAP];     // 72 KB
    __shared__ int cnt[KEYS];           // 16 KB
    __shared__ int ssum[512];           // 2 KB
    int b = blockIdx.x, t = threadIdx.x;
    int lo = bbase[b], hi = bbase[b + 1];
    int m = hi - lo;
    int staged = (m < P2_CAP) ? m : P2_CAP;
    for (int i = t; i < staged; i += 512) sedge[i] = coarse[lo + i];
    for (int k = t; k < KEYS; k += 512) cnt[k] = 0;
    __syncthreads();
    for (int i = t; i < m; i += 512) {
        uint2 r = (i < staged) ? sedge[i] : coarse[lo + i];
        unsigned key = ((r.x & (BKT_NODES - 1)) << 3) | ((r.x >> BKT_SHIFT) >> TILE_SHIFT);
        atomicAdd(&cnt[key], 1);
    }
    __syncthreads();
    int base = t << 3;
    int local[NTILE];
    int s = 0;
#pragma unroll
    for (int j = 0; j < NTILE; ++j) { local[j] = s; s += cnt[base + j]; }
    ssum[t] = s;
    __syncthreads();
    for (int off = 1; off < 512; off <<= 1) {
        int u = (t >= off) ? ssum[t - off] : 0;
        __syncthreads();
        ssum[t] += u;
        __syncthreads();
    }
    int pre = lo + ssum[t] - s;          // exclusive prefix of this thread's keys
    int node = (b << BKT_SHIFT) + t;
    if (node < N_NODES) row_ptr[node] = pre;
#pragma unroll
    for (int j = 0; j < NTILE; ++j) cnt[base + j] = pre + local[j];
    __syncthreads();
    for (int i = t; i < m; i += 512) {
        uint2 r = (i < staged) ? sedge[i] : coarse[lo + i];
        unsigned src = r.x >> BKT_SHIFT;
        unsigned key = ((r.x & (BKT_NODES - 1)) << 3) | (src >> TILE_SHIFT);
        int pos = atomicAdd(&cnt[key], 1);
        recs[pos] = make_int2((int)src, (int)r.y);
    }
}

// ---------- SpMM gather (bf16 features, f32 accumulate, unroll 4) ----------
__device__ __forceinline__ void acc4(float* a, ushort4 u, float w) {
    a[0] += w * bf2f(u.x);
    a[1] += w * bf2f(u.y);
    a[2] += w * bf2f(u.z);
    a[3] += w * bf2f(u.w);
}

template <bool OUT_BF16>
__global__ void spmm_gather_b_kernel(const unsigned short* __restrict__ xb,
                                     const int2* __restrict__ recs,
                                     const int*  __restrict__ row_ptr,
                                     void* __restrict__ outv) {
    int tid = blockIdx.x * blockDim.x + threadIdx.x;
    int n = tid >> 2;
    int l = tid & 3;
    if (n >= N_NODES) return;
    int e   = row_ptr[n];
    int end = row_ptr[n + 1];
    float a0[4] = {0.f, 0.f, 0.f, 0.f};
    float a1[4] = {0.f, 0.f, 0.f, 0.f};
    float a2[4] = {0.f, 0.f, 0.f, 0.f};
    const ushort4* __restrict__ X = reinterpret_cast<const ushort4*>(xb);
    for (; e + 3 < end; e += 4) {
        int2 r0 = recs[e],     r1 = recs[e + 1];
        int2 r2 = recs[e + 2], r3 = recs[e + 3];
        const ushort4* x0 = X + (size_t)r0.x * (D_FEAT / 4);
        const ushort4* x1 = X + (size_t)r1.x * (D_FEAT / 4);
        const ushort4* x2 = X + (size_t)r2.x * (D_FEAT / 4);
        const ushort4* x3 = X + (size_t)r3.x * (D_FEAT / 4);
        ushort4 u00 = x0[l], u01 = x0[4 + l], u02 = x0[8 + l];
        ushort4 u10 = x1[l], u11 = x1[4 + l], u12 = x1[8 + l];
        ushort4 u20 = x2[l], u21 = x2[4 + l], u22 = x2[8 + l];
        ushort4 u30 = x3[l], u31 = x3[4 + l], u32 = x3[8 + l];
        float w0 = __int_as_float(r0.y), w1 = __int_as_float(r1.y);
        float w2 = __int_as_float(r2.y), w3 = __int_as_float(r3.y);
        acc4(a0, u00, w0); acc4(a1, u01, w0); acc4(a2, u02, w0);
        acc4(a0, u10, w1); acc4(a1, u11, w1); acc4(a2, u12, w1);
        acc4(a0, u20, w2); acc4(a1, u21, w2); acc4(a2, u22, w2);
        acc4(a0, u30, w3); acc4(a1, u31, w3); acc4(a2, u32, w3);
    }
    for (; e < end; ++e) {
        int2 r = recs[e];
        float we = __int_as_float(r.y);
        const ushort4* xr = X + (size_t)r.x * (D_FEAT / 4);
        acc4(a0, xr[l], we); acc4(a1, xr[4 + l], we); acc4(a2, xr[8 + l], we);
    }
    if (OUT_BF16) {
        ushort4* orow = reinterpret_cast<ushort4*>((unsigned short*)outv + (size_t)n * D_FEAT);
        ushort4 o0, o1, o2;
        o0.x = bf16_rn(a0[0]); o0.y = bf16_rn(a0[1]); o0.z = bf16_rn(a0[2]); o0.w = bf16_rn(a0[3]);
        o1.x = bf16_rn(a1[0]); o1.y = bf16_rn(a1[1]); o1.z = bf16_rn(a1[2]); o1.w = bf16_rn(a1[3]);
        o2.x = bf16_rn(a2[0]); o2.y = bf16_rn(a2[1]); o2.z = bf16_rn(a2[2]); o2.w = bf16_rn(a2[3]);
        orow[l] = o0; orow[4 + l] = o1; orow[8 + l] = o2;
    } else {
        float4* orow = reinterpret_cast<float4*>((float*)outv + (size_t)n * D_FEAT);
        orow[l]     = make_float4(a0[0], a0[1], a0[2], a0[3]);
        orow[4 + l] = make_float4(a1[0], a1[1], a1[2], a1[3]);
        orow[8 + l] = make_float4(a2[0], a2[1], a2[2], a2[3]);
    }
}

extern "C" void kernel_launch(void* const* d_in, const int* in_sizes, int n_in,
                              void* d_out, int out_size, void* d_ws, size_t ws_size,
                              hipStream_t stream) {
    const float* x    = (const float*)d_in[0];
    const float* ew   = (const float*)d_in[1];
    const int*   esrc = (const int*)d_in[2];
    const int*   edst = (const int*)d_in[3];
    float* out = (float*)d_out;

    // Workspace layout. tmpb (bf16, 9.6 MB) shares its slot with coarse
    // (12.8 MB): p2 consumes coarse before spmm pass 1 writes tmpb.
    char* ws = (char*)d_ws;
    unsigned short* xb = (unsigned short*)ws;                 // 9.6 MB
    ws += (((size_t)N_NODES * D_FEAT * sizeof(unsigned short)) + 15) & ~15ull;
    unsigned short* tmpb = (unsigned short*)ws;
    uint2* coarse = (uint2*)ws;
    ws += (size_t)N_EDGES * sizeof(uint2);
    int2* recs = (int2*)ws;                                   // 12.8 MB
    ws += (size_t)N_EDGES * sizeof(int2);
    int* row_ptr = (int*)ws;
    ws += ((size_t)(N_NODES + 1) * sizeof(int) + 15) & ~15ull;
    int* ccount = (int*)ws;
    ws += ((size_t)NBKT * sizeof(int) + 15) & ~15ull;
    int* bbase = (int*)ws;
    ws += ((size_t)(NBKT + 1) * sizeof(int) + 15) & ~15ull;
    int* cursor = (int*)ws;

    dim3 blk(256);
    dim3 grid_nodes(((size_t)N_NODES * 4 + 255) / 256);

    // CSR build + bf16 conversion
    hipMemsetAsync(ccount, 0, NBKT * sizeof(int), stream);
    cvt_hist_kernel<<<1024, blk, 0, stream>>>(x, xb, edst, ccount);
    scan196_kernel<<<1, blk, 0, stream>>>(ccount, bbase, cursor, row_ptr);
    p1_kernel<<<NB1, blk, 0, stream>>>(ew, esrc, edst, cursor, coarse);
    p2_kernel<<<NBKT, dim3(512), 0, stream>>>(coarse, bbase, recs, row_ptr);

    // Pass 1: tmpb = bf16(A @ xb) ; Pass 2: out = A @ tmpb (f32 out)
    spmm_gather_b_kernel<true><<<grid_nodes, blk, 0, stream>>>(xb, recs, row_ptr, tmpb);
    spmm_gather_b_kernel<false><<<grid_nodes, blk, 0, stream>>>(tmpb, recs, row_ptr, out);
}